// Round 7
// baseline (570.440 us; speedup 1.0000x reference)
//
#include <hip/hip_runtime.h>

typedef short bf16x8 __attribute__((ext_vector_type(8)));
typedef float f32x16 __attribute__((ext_vector_type(16)));

__device__ __forceinline__ unsigned short f2bf(float x) {
    unsigned u = __float_as_uint(x);
    return (unsigned short)((u + 0x7FFFu + ((u >> 16) & 1u)) >> 16);
}
__device__ __forceinline__ float bf2f(unsigned short h) {
    return __uint_as_float(((unsigned)h) << 16);
}
__device__ __forceinline__ unsigned score_key(float s) {
    unsigned u = __float_as_uint(s);
    return (u & 0x80000000u) ? ~u : (u | 0x80000000u);
}
// fp32[8] -> packed bf16 hi uint4 + lo uint4 (RNE both stages; absmax-0 verified math)
__device__ __forceinline__ void split8m(const float4& fa, const float4& fb,
                                        uint4& hv, uint4& lv) {
    const float f[8] = {fa.x, fa.y, fa.z, fa.w, fb.x, fb.y, fb.z, fb.w};
    unsigned H[4], L[4];
#pragma unroll
    for (int q = 0; q < 4; ++q) {
        const float x0 = f[2 * q], x1 = f[2 * q + 1];
        const unsigned short h0 = f2bf(x0), h1 = f2bf(x1);
        const unsigned short l0 = f2bf(x0 - bf2f(h0));
        const unsigned short l1 = f2bf(x1 - bf2f(h1));
        H[q] = (unsigned)h0 | ((unsigned)h1 << 16);
        L[q] = (unsigned)l0 | ((unsigned)l1 << 16);
    }
    hv = make_uint4(H[0], H[1], H[2], H[3]);
    lv = make_uint4(L[0], L[1], L[2], L[3]);
}
__device__ __forceinline__ void async_cp16(const uint4* g, uint4* l) {
    __builtin_amdgcn_global_load_lds(
        (const __attribute__((address_space(1))) unsigned int*)g,
        (__attribute__((address_space(3))) unsigned int*)l, 16, 0, 0);
}

// v[j] = sum_o W2[j,o]*Ws[o];  v[256] = dot(b2,Ws) + bs
__global__ void prep_kernel(const float* __restrict__ W2, const float* __restrict__ b2,
                            const float* __restrict__ Ws, const float* __restrict__ bs,
                            float* __restrict__ v, int OUT) {
    int j = threadIdx.x;
    float acc = 0.f;
    for (int o = 0; o < OUT; ++o) acc += W2[j * OUT + o] * Ws[o];
    v[j] = acc;
    if (j == 0) {
        float c = bs[0];
        for (int o = 0; o < OUT; ++o) c += b2[o] * Ws[o];
        v[256] = c;
    }
}

// W1 [256][256] -> 32x32x16 fragment pack, hi/lo (layout absmax-0 verified in R4-R6)
// uint4 idx = kt*2048 + (hl*16 + nt*2 + kc)*64 + lane
// elem j of slot = W1[kt*32 + kc*16 + (lane>>5)*8 + j][nt*32 + (lane&31)]
__global__ void prep_w1frag(const float* __restrict__ W1, uint4* __restrict__ wfrag) {
    const int s = blockIdx.x * 256 + threadIdx.x;   // 0..16383
    const int kt = s >> 11;
    const int c = (s >> 6) & 31;
    const int lane = s & 63;
    const int hl = c >> 4;
    const int nt = (c >> 1) & 7;
    const int kc = c & 1;
    const int col = nt * 32 + (lane & 31);
    const int k0 = kt * 32 + kc * 16 + (lane >> 5) * 8;
    unsigned pk[4];
#pragma unroll
    for (int q = 0; q < 4; ++q) {
        float x0 = W1[(size_t)(k0 + 2 * q) * 256 + col];
        float x1 = W1[(size_t)(k0 + 2 * q + 1) * 256 + col];
        unsigned short a0, a1;
        if (hl == 0) { a0 = f2bf(x0); a1 = f2bf(x1); }
        else {
            a0 = f2bf(x0 - bf2f(f2bf(x0)));
            a1 = f2bf(x1 - bf2f(f2bf(x1)));
        }
        pk[q] = (unsigned)a0 | ((unsigned)a1 << 16);
    }
    wfrag[s] = make_uint4(pk[0], pk[1], pk[2], pk[3]);
}

// desc -> A-fragments (bf16 hi/lo), mirroring wfrag's (lane,elem)->k bijection.
// afrag uint4 idx = ((tile*8 + kt)*2 + kc)*128 + hl*64 + lane
// elem j = desc[tile*32 + (lane&31)][kt*32 + kc*16 + (lane>>5)*8 + j]
__global__ void prep_afrag(const float* __restrict__ desc, uint4* __restrict__ afrag,
                           int ntiles, int total) {
    const int gid = blockIdx.x * 256 + threadIdx.x;
    if (gid >= ntiles * 1024) return;
    const int lane = gid & 63;
    const int kc = (gid >> 6) & 1;
    const int kt = (gid >> 7) & 7;
    const int tile = gid >> 10;
    const int row = min(tile * 32 + (lane & 31), total - 1);
    const int k0 = kt * 32 + kc * 16 + (lane >> 5) * 8;
    const float* p = desc + (size_t)row * 256 + k0;
    const float4 a = *(const float4*)p;
    const float4 b = *(const float4*)(p + 4);
    uint4 hv, lv;
    split8m(a, b, hv, lv);
    uint4* o = afrag + (size_t)(gid >> 6) * 128 + lane;
    o[0] = hv;
    o[64] = lv;
}

__global__ void init_bins(unsigned long long* __restrict__ bins, int n) {
    int i = blockIdx.x * blockDim.x + threadIdx.x;
    if (i < n) bins[i] = 0ULL;
}

// 4 waves/block, wave = 32 rows x 256 cols (row-split). B: shared LDS dbuf via
// global_load_lds; raw s_barrier + counted vmcnt (never drain). A: coalesced
// prepacked frags (MODE0) or fp32 + in-kernel split (MODE1 fallback).
template<int MODE>
__global__ __launch_bounds__(256, 2) void score_kernel(
    const float* __restrict__ desc, const uint4* __restrict__ afrag,
    const float* __restrict__ kpts, const uint4* __restrict__ wfrag,
    const float* __restrict__ b1, const float* __restrict__ g1, const float* __restrict__ be1,
    const int* __restrict__ Hp, const int* __restrict__ Wp,
    const float* __restrict__ v,
    float* __restrict__ scores, unsigned long long* __restrict__ bins,
    int N, int total)
{
    __shared__ uint4 BS[2][2048];   // double-buffered W1 frags (2 x 32KB)

    const int t = threadIdx.x;
    const int lane = t & 63;
    const int w = t >> 6;                 // wave 0..3 (row-split)
    const int c31 = lane & 31;
    const int h = lane >> 5;
    const int tile = blockIdx.x * 4 + w;  // 32-row tile owned by this wave
    const int R0 = tile * 32;

    // ---- prologue: stage B[0]; load A[0]
    {
        const uint4* bsrc = wfrag + t;
#pragma unroll
        for (int j = 0; j < 8; ++j)
            async_cp16(bsrc + j * 256, &BS[0][j * 256 + t]);
    }

    const uint4* pa = nullptr;
    const float* pf = nullptr;
    if (MODE == 0) {
        pa = afrag + (size_t)tile * 2048 + lane;   // kt stride 256, kc stride 128, hl 64
    } else {
        const int rA = min(R0 + c31, total - 1);
        pf = desc + (size_t)rA * 256 + h * 8;
    }

    uint4 A0[4];   // kc0-hi, kc0-lo, kc1-hi, kc1-lo
    float4 F0[4];
    if (MODE == 0) {
        A0[0] = pa[0];   A0[1] = pa[64];
        A0[2] = pa[128]; A0[3] = pa[192];
    } else {
        F0[0] = *(const float4*)(pf + 0);  F0[1] = *(const float4*)(pf + 4);
        F0[2] = *(const float4*)(pf + 16); F0[3] = *(const float4*)(pf + 20);
    }

    f32x16 acc[8];
#pragma unroll
    for (int nt = 0; nt < 8; ++nt) {
        const float bc = b1[nt * 32 + c31];   // fold b1 into acc init (col-constant)
#pragma unroll
        for (int r = 0; r < 16; ++r) acc[nt][r] = bc;
    }

#pragma unroll
    for (int kt = 0; kt < 8; ++kt) {
        const int cur = kt & 1;
        __builtin_amdgcn_s_barrier();            // #1: all waves done reading buf[cur^1]

        uint4 A1[4]; float4 F1[4];
        if (kt < 7) {
            // issue stage B[kt+1] (8 glds) + load A[kt+1] (4 loads); all stay in flight
            const uint4* bsrc = wfrag + (size_t)(kt + 1) * 2048 + t;
#pragma unroll
            for (int j = 0; j < 8; ++j)
                async_cp16(bsrc + j * 256, &BS[cur ^ 1][j * 256 + t]);
            if (MODE == 0) {
                const uint4* pn = pa + (size_t)(kt + 1) * 256;
                A1[0] = pn[0];   A1[1] = pn[64];
                A1[2] = pn[128]; A1[3] = pn[192];
            } else {
                const float* pn = pf + (kt + 1) * 32;
                F1[0] = *(const float4*)(pn + 0);  F1[1] = *(const float4*)(pn + 4);
                F1[2] = *(const float4*)(pn + 16); F1[3] = *(const float4*)(pn + 20);
            }
            // counted wait: own stage[kt] done; 16 newest (A[kt]4 + stage[kt+1]8 + A[kt+1]4) may fly
            asm volatile("s_waitcnt vmcnt(16)" ::: "memory");
        } else {
            asm volatile("s_waitcnt vmcnt(4)" ::: "memory");   // stage[7] done; A[7] may fly
        }
        __builtin_amdgcn_s_barrier();            // #2: ALL waves' stage[kt] visible in LDS

        bf16x8 ah0, al0, ah1, al1;
        if (MODE == 0) {
            ah0 = *reinterpret_cast<const bf16x8*>(&A0[0]);
            al0 = *reinterpret_cast<const bf16x8*>(&A0[1]);
            ah1 = *reinterpret_cast<const bf16x8*>(&A0[2]);
            al1 = *reinterpret_cast<const bf16x8*>(&A0[3]);
        } else {
            uint4 hv, lv;
            split8m(F0[0], F0[1], hv, lv);
            ah0 = *reinterpret_cast<const bf16x8*>(&hv);
            al0 = *reinterpret_cast<const bf16x8*>(&lv);
            split8m(F0[2], F0[3], hv, lv);
            ah1 = *reinterpret_cast<const bf16x8*>(&hv);
            al1 = *reinterpret_cast<const bf16x8*>(&lv);
        }

        // kc = 0  (pass-major: same-acc distance 8)
        {
            bf16x8 bq[8];
#pragma unroll
            for (int nt = 0; nt < 8; ++nt)
                bq[nt] = *(const bf16x8*)&BS[cur][(nt * 2 + 0) * 64 + lane];      // hi
#pragma unroll
            for (int nt = 0; nt < 8; ++nt)
                acc[nt] = __builtin_amdgcn_mfma_f32_32x32x16_bf16(ah0, bq[nt], acc[nt], 0, 0, 0);
#pragma unroll
            for (int nt = 0; nt < 8; ++nt)
                acc[nt] = __builtin_amdgcn_mfma_f32_32x32x16_bf16(al0, bq[nt], acc[nt], 0, 0, 0);
#pragma unroll
            for (int nt = 0; nt < 8; ++nt)
                bq[nt] = *(const bf16x8*)&BS[cur][(16 + nt * 2 + 0) * 64 + lane]; // lo
#pragma unroll
            for (int nt = 0; nt < 8; ++nt)
                acc[nt] = __builtin_amdgcn_mfma_f32_32x32x16_bf16(ah0, bq[nt], acc[nt], 0, 0, 0);
#pragma unroll
            for (int nt = 0; nt < 8; ++nt)
                acc[nt] = __builtin_amdgcn_mfma_f32_32x32x16_bf16(al0, bq[nt], acc[nt], 0, 0, 0);
        }
        // kc = 1
        {
            bf16x8 bq[8];
#pragma unroll
            for (int nt = 0; nt < 8; ++nt)
                bq[nt] = *(const bf16x8*)&BS[cur][(nt * 2 + 1) * 64 + lane];      // hi
#pragma unroll
            for (int nt = 0; nt < 8; ++nt)
                acc[nt] = __builtin_amdgcn_mfma_f32_32x32x16_bf16(ah1, bq[nt], acc[nt], 0, 0, 0);
#pragma unroll
            for (int nt = 0; nt < 8; ++nt)
                acc[nt] = __builtin_amdgcn_mfma_f32_32x32x16_bf16(al1, bq[nt], acc[nt], 0, 0, 0);
#pragma unroll
            for (int nt = 0; nt < 8; ++nt)
                bq[nt] = *(const bf16x8*)&BS[cur][(16 + nt * 2 + 1) * 64 + lane]; // lo
#pragma unroll
            for (int nt = 0; nt < 8; ++nt)
                acc[nt] = __builtin_amdgcn_mfma_f32_32x32x16_bf16(ah1, bq[nt], acc[nt], 0, 0, 0);
#pragma unroll
            for (int nt = 0; nt < 8; ++nt)
                acc[nt] = __builtin_amdgcn_mfma_f32_32x32x16_bf16(al1, bq[nt], acc[nt], 0, 0, 0);
        }
        if (kt < 7) {
            if (MODE == 0) { A0[0]=A1[0]; A0[1]=A1[1]; A0[2]=A1[2]; A0[3]=A1[3]; }
            else           { F0[0]=F1[0]; F0[1]=F1[1]; F0[2]=F1[2]; F0[3]=F1[3]; }
        }
    }

    // ---- in-wave epilogue (verified R6). C/D: rowIn32=(reg&3)+8*(reg>>2)+4*h, col=nt*32+c31
    float gE[8], beE[8], vE[8];
#pragma unroll
    for (int nt = 0; nt < 8; ++nt) {
        const int c = nt * 32 + c31;
        gE[nt] = g1[c]; beE[nt] = be1[c]; vE[nt] = v[c];
    }
    const float Wf = (float)Wp[0];
    const int Hi = Hp[0];
    const float t02 = (float)(0.2 * (double)Hi);
    const float t05 = (float)(0.5 * (double)Hi);
    const float t03 = (float)(0.3 * (double)Hi);
    const float cterm = v[256];

#pragma unroll
    for (int reg = 0; reg < 16; ++reg) {
        float sx = 0.f, sq = 0.f;
#pragma unroll
        for (int nt = 0; nt < 8; ++nt) {
            const float x = acc[nt][reg];
            sx += x; sq = fmaf(x, x, sq);
        }
#pragma unroll
        for (int m = 1; m <= 16; m <<= 1) {
            sx += __shfl_xor(sx, m);
            sq += __shfl_xor(sq, m);
        }
        const float mu = sx * (1.f / 256.f);
        const float var = sq * (1.f / 256.f) - mu * mu;
        const float rs = 1.f / sqrtf(var + 1e-5f);
        float dot = 0.f;
#pragma unroll
        for (int nt = 0; nt < 8; ++nt) {
            const float hv = (acc[nt][reg] - mu) * rs * gE[nt] + beE[nt];
            const float sg = 1.f / (1.f + __expf(-hv));
            dot = fmaf(vE[nt], hv * sg, dot);
        }
#pragma unroll
        for (int m = 1; m <= 16; m <<= 1) dot += __shfl_xor(dot, m);

        if (c31 == 0) {
            const int row = R0 + (reg & 3) + 8 * (reg >> 2) + 4 * h;
            if (row < total) {
                const float sc = dot + cterm;
                scores[row] = sc;
                const float x = kpts[(size_t)row * 2 + 0];
                const float y = kpts[(size_t)row * 2 + 1];
                int g = -1;
                if (y > t05) {
                    int bgx = (int)(x / Wf * 16.f); bgx = min(max(bgx, 0), 15);
                    int bgy = (int)((y - t05) / t05 * 6.f); bgy = min(max(bgy, 0), 5);
                    g = 32 + bgy * 16 + bgx;
                } else if (y > t02) {
                    int mgx = (int)(x / Wf * 8.f); mgx = min(max(mgx, 0), 7);
                    int mgy = (int)((y - t02) / t03 * 4.f); mgy = min(max(mgy, 0), 3);
                    g = mgy * 8 + mgx;
                }
                if (g >= 0) {
                    const int bb = row / N;
                    const int n = row - bb * N;
                    const unsigned long long pk =
                        ((unsigned long long)score_key(sc) << 32) | (unsigned)(~(unsigned)n);
                    atomicMax(&bins[bb * 128 + g], pk);
                }
            }
        }
    }
}

// One block per batch: compact bin winners (bin order), top-k fallback, gather outputs.
__global__ __launch_bounds__(256) void finalize_kernel(
    const float* __restrict__ scores, const unsigned long long* __restrict__ bins,
    const float* __restrict__ desc, const float* __restrict__ kpts,
    const int* __restrict__ tkp, float* __restrict__ out, int B, int N)
{
    const int b = blockIdx.x, t = threadIdx.x;
    const int topk = tkp[0];
    __shared__ int selL[512];
    __shared__ int nselS;
    __shared__ unsigned long long red[256];
    __shared__ unsigned long long binL[128];

    if (t < 128) binL[t] = bins[b * 128 + t];
    __syncthreads();
    if (t == 0) {
        int c = 0;
        for (int i = 0; i < 128; ++i)
            if ((binL[i] >> 32) != 0ULL) selL[c++] = (int)(~(unsigned)binL[i]);
        nselS = c;
    }
    __syncthreads();
    const int nsel = nselS;

    for (int need = nsel; need < topk; ++need) {
        unsigned long long best = 0ULL;
        for (int i = t; i < N; i += 256) {
            bool taken = false;
            for (int s2 = 0; s2 < need; ++s2)
                if (selL[s2] == i) { taken = true; break; }
            if (!taken) {
                const unsigned long long pk =
                    ((unsigned long long)score_key(scores[(size_t)b * N + i]) << 32)
                    | (unsigned)(~(unsigned)i);
                if (pk > best) best = pk;
            }
        }
        red[t] = best;
        __syncthreads();
        for (int off = 128; off > 0; off >>= 1) {
            if (t < off) { if (red[t + off] > red[t]) red[t] = red[t + off]; }
            __syncthreads();
        }
        if (t == 0) selL[need] = (int)(~(unsigned)red[0]);
        __syncthreads();
    }

    float* o_feat = out;
    float* o_kpts = out + (size_t)B * topk * 256;
    float* o_idx  = out + (size_t)B * topk * 258;
    for (int e = t; e < topk * 64; e += 256) {
        const int j = e >> 6, q4 = e & 63;
        const int n = selL[j];
        *(float4*)&o_feat[((size_t)b * topk + j) * 256 + q4 * 4] =
            *(const float4*)&desc[((size_t)b * N + n) * 256 + q4 * 4];
    }
    for (int j = t; j < topk; j += 256) {
        const int n = selL[j];
        o_kpts[((size_t)b * topk + j) * 2 + 0] = kpts[((size_t)b * N + n) * 2 + 0];
        o_kpts[((size_t)b * topk + j) * 2 + 1] = kpts[((size_t)b * N + n) * 2 + 1];
        o_idx[(size_t)b * topk + j] = (float)n;
    }
}

extern "C" void kernel_launch(void* const* d_in, const int* in_sizes, int n_in,
                              void* d_out, int out_size, void* d_ws, size_t ws_size,
                              hipStream_t stream) {
    const float* kpts = (const float*)d_in[0];
    const float* desc = (const float*)d_in[1];
    const int*   Hp   = (const int*)d_in[2];
    const int*   Wp   = (const int*)d_in[3];
    const int*   tkp  = (const int*)d_in[4];
    const float* W1   = (const float*)d_in[5];
    const float* b1   = (const float*)d_in[6];
    const float* g1   = (const float*)d_in[7];
    const float* be1  = (const float*)d_in[8];
    const float* W2   = (const float*)d_in[9];
    const float* b2   = (const float*)d_in[10];
    const float* Ws   = (const float*)d_in[11];
    const float* bs   = (const float*)d_in[12];

    const int total = in_sizes[1] / 256;   // B*N
    const int BT    = out_size / 259;      // B*topk
    const int B     = BT / 128;            // topk = 128 for this problem
    const int N     = total / B;
    const int OUT   = in_sizes[11];        // 128
    const int ntiles = (total + 31) / 32;

    float* ws_v      = (float*)d_ws;                       // 257 floats (pad 512)
    float* ws_scores = ws_v + 512;                         // total floats
    size_t off = ((size_t)(512 + total) * 4 + 255) & ~(size_t)255;
    unsigned long long* ws_bins = (unsigned long long*)((char*)d_ws + off);
    size_t off2 = (off + (size_t)B * 128 * 8 + 255) & ~(size_t)255;
    uint4* ws_wfrag = (uint4*)((char*)d_ws + off2);        // 16384 uint4 = 256KB
    size_t off3 = (off2 + 16384 * 16 + 255) & ~(size_t)255;
    uint4* ws_afrag = (uint4*)((char*)d_ws + off3);        // ntiles*2048 uint4
    const size_t afrag_bytes = (size_t)ntiles * 2048 * 16;
    const bool presplit = (off3 + afrag_bytes) <= ws_size;

    prep_kernel<<<1, 256, 0, stream>>>(W2, b2, Ws, bs, ws_v, OUT);
    prep_w1frag<<<64, 256, 0, stream>>>(W1, ws_wfrag);
    init_bins<<<(B * 128 + 255) / 256, 256, 0, stream>>>(ws_bins, B * 128);

    const int gemm_blocks = (ntiles + 3) / 4;
    if (presplit) {
        prep_afrag<<<(ntiles * 1024 + 255) / 256, 256, 0, stream>>>(desc, ws_afrag, ntiles, total);
        score_kernel<0><<<gemm_blocks, 256, 0, stream>>>(
            desc, ws_afrag, kpts, ws_wfrag, b1, g1, be1, Hp, Wp, ws_v,
            ws_scores, ws_bins, N, total);
    } else {
        score_kernel<1><<<gemm_blocks, 256, 0, stream>>>(
            desc, ws_afrag, kpts, ws_wfrag, b1, g1, be1, Hp, Wp, ws_v,
            ws_scores, ws_bins, N, total);
    }
    finalize_kernel<<<B, 256, 0, stream>>>(ws_scores, ws_bins, desc, kpts, tkp,
                                           (float*)d_out, B, N);
}

// Round 8
// 531.743 us; speedup vs baseline: 1.0728x; 1.0728x over previous
//
#include <hip/hip_runtime.h>

typedef short bf16x8 __attribute__((ext_vector_type(8)));
typedef float f32x16 __attribute__((ext_vector_type(16)));

__device__ __forceinline__ unsigned short f2bf(float x) {
    unsigned u = __float_as_uint(x);
    return (unsigned short)((u + 0x7FFFu + ((u >> 16) & 1u)) >> 16);
}
__device__ __forceinline__ float bf2f(unsigned short h) {
    return __uint_as_float(((unsigned)h) << 16);
}
__device__ __forceinline__ unsigned score_key(float s) {
    unsigned u = __float_as_uint(s);
    return (u & 0x80000000u) ? ~u : (u | 0x80000000u);
}
// fp32[8] -> bf16 hi + lo fragments (absmax-0 verified math, R2-R7)
__device__ __forceinline__ void split8m(const float4& fa, const float4& fb,
                                        bf16x8& hv, bf16x8& lv) {
    const float f[8] = {fa.x, fa.y, fa.z, fa.w, fb.x, fb.y, fb.z, fb.w};
    union { unsigned w[4]; bf16x8 v; } H, L;
#pragma unroll
    for (int q = 0; q < 4; ++q) {
        const float x0 = f[2 * q], x1 = f[2 * q + 1];
        const unsigned short h0 = f2bf(x0), h1 = f2bf(x1);
        const unsigned short l0 = f2bf(x0 - bf2f(h0));
        const unsigned short l1 = f2bf(x1 - bf2f(h1));
        H.w[q] = (unsigned)h0 | ((unsigned)h1 << 16);
        L.w[q] = (unsigned)l0 | ((unsigned)l1 << 16);
    }
    hv = H.v; lv = L.v;
}
__device__ __forceinline__ void async_cp16(const uint4* g, uint4* l) {
    __builtin_amdgcn_global_load_lds(
        (const __attribute__((address_space(1))) unsigned int*)g,
        (__attribute__((address_space(3))) unsigned int*)l, 16, 0, 0);
}

__global__ void prep_kernel(const float* __restrict__ W2, const float* __restrict__ b2,
                            const float* __restrict__ Ws, const float* __restrict__ bs,
                            float* __restrict__ v, int OUT) {
    int j = threadIdx.x;
    float acc = 0.f;
    for (int o = 0; o < OUT; ++o) acc += W2[j * OUT + o] * Ws[o];
    v[j] = acc;
    if (j == 0) {
        float c = bs[0];
        for (int o = 0; o < OUT; ++o) c += b2[o] * Ws[o];
        v[256] = c;
    }
}

// W1 fragment pack (absmax-0 verified R4-R7)
__global__ void prep_w1frag(const float* __restrict__ W1, uint4* __restrict__ wfrag) {
    const int s = blockIdx.x * 256 + threadIdx.x;
    const int kt = s >> 11;
    const int c = (s >> 6) & 31;
    const int lane = s & 63;
    const int hl = c >> 4;
    const int nt = (c >> 1) & 7;
    const int kc = c & 1;
    const int col = nt * 32 + (lane & 31);
    const int k0 = kt * 32 + kc * 16 + (lane >> 5) * 8;
    unsigned pk[4];
#pragma unroll
    for (int q = 0; q < 4; ++q) {
        float x0 = W1[(size_t)(k0 + 2 * q) * 256 + col];
        float x1 = W1[(size_t)(k0 + 2 * q + 1) * 256 + col];
        unsigned short a0, a1;
        if (hl == 0) { a0 = f2bf(x0); a1 = f2bf(x1); }
        else {
            a0 = f2bf(x0 - bf2f(f2bf(x0)));
            a1 = f2bf(x1 - bf2f(f2bf(x1)));
        }
        pk[q] = (unsigned)a0 | ((unsigned)a1 << 16);
    }
    wfrag[s] = make_uint4(pk[0], pk[1], pk[2], pk[3]);
}

__global__ void init_bins(unsigned long long* __restrict__ bins, int n) {
    int i = blockIdx.x * blockDim.x + threadIdx.x;
    if (i < n) bins[i] = 0ULL;
}

// 512 thr = 8 waves (4 rg x 2 cg); wave = 64 rows x 128 cols. BM=256, BK=32.
// 2 fine phases per kt {ds_reads || stage-issue || split -> bar -> setprio MFMA -> bar};
// counted vmcnt at kt tail only; A reg-staged with XOR-swizzled LDS; B gld_lds dbuf.
__global__ __launch_bounds__(512, 2) void score_kernel(
    const float* __restrict__ desc, const float* __restrict__ kpts,
    const uint4* __restrict__ wfrag,
    const float* __restrict__ b1, const float* __restrict__ g1, const float* __restrict__ be1,
    const int* __restrict__ Hp, const int* __restrict__ Wp,
    const float* __restrict__ v,
    float* __restrict__ scores, unsigned long long* __restrict__ bins,
    int N, int total)
{
    __shared__ uint4 BS[2][2048];        // 64 KB B frags dbuf
    __shared__ float AS[2][256 * 32];    // 64 KB A fp32 dbuf (swizzled chunks)
    __shared__ float sums2[256][4];
    __shared__ float dot2[256][2];

    const int t = threadIdx.x;
    const int lane = t & 63;
    const int w = t >> 6;
    const int rg = w >> 1, cg = w & 1;
    const int c31 = lane & 31;
    const int h = lane >> 5;
    const int R0T = blockIdx.x * 256;

    // A-stage addressing: u = j*512+t -> row u>>3, chunk u&7 (16B)
    int arow[4], alds[4];
    const float* asrc[4];
#pragma unroll
    for (int j = 0; j < 4; ++j) {
        const int u = j * 512 + t;
        const int r = u >> 3, ck = u & 7;
        arow[j] = r;
        alds[j] = r * 32 + ((ck ^ (r & 7)) << 2);          // swizzled float offset
        asrc[j] = desc + (size_t)min(R0T + r, total - 1) * 256 + ck * 4;
    }

    f32x16 acc[2][4];
#pragma unroll
    for (int m = 0; m < 2; ++m)
#pragma unroll
        for (int j = 0; j < 4; ++j) {
            const float bc = b1[cg * 128 + j * 32 + c31];
#pragma unroll
            for (int r = 0; r < 16; ++r) acc[m][j][r] = bc;
        }

    // ---- prologue: B[0] stage, A[0] -> LDS, A[1] -> regs
    uint4 Acur[4], Anxt[4];
    {
#pragma unroll
        for (int js = 0; js < 4; ++js)
            async_cp16(wfrag + js * 512 + t, &BS[0][js * 512 + t]);
#pragma unroll
        for (int j = 0; j < 4; ++j) Acur[j] = *(const uint4*)(asrc[j]);
        asm volatile("s_waitcnt vmcnt(0)" ::: "memory");
#pragma unroll
        for (int j = 0; j < 4; ++j) *(uint4*)&AS[0][alds[j]] = Acur[j];
#pragma unroll
        for (int j = 0; j < 4; ++j) Acur[j] = *(const uint4*)(asrc[j] + 32);
        asm volatile("s_waitcnt lgkmcnt(0)" ::: "memory");
        __builtin_amdgcn_sched_barrier(0);
        __builtin_amdgcn_s_barrier();
    }

    const int rowL0 = rg * 64 + c31;      // m=0 local row
    const int swz = c31 & 7;

#pragma unroll
    for (int kt = 0; kt < 8; ++kt) {
        const int cur = kt & 1;
#pragma unroll
        for (int kc = 0; kc < 2; ++kc) {
            // A-lds reads + split (both m)
            bf16x8 ah[2], al[2];
#pragma unroll
            for (int m = 0; m < 2; ++m) {
                const int row = rowL0 + m * 32;
                const int base = kc * 4 + h * 2;
                const float4 f0 = *(const float4*)&AS[cur][row * 32 + ((base ^ swz) << 2)];
                const float4 f1 = *(const float4*)&AS[cur][row * 32 + (((base + 1) ^ swz) << 2)];
                split8m(f0, f1, ah[m], al[m]);
            }
            // B-lds reads (this cg's 4 nt, this kc, hi+lo)
            bf16x8 bh[4], bl[4];
#pragma unroll
            for (int j = 0; j < 4; ++j) {
                const int ch = (cg * 4 + j) * 2 + kc;
                bh[j] = *(const bf16x8*)&BS[cur][ch * 64 + lane];
                bl[j] = *(const bf16x8*)&BS[cur][(16 + ch) * 64 + lane];
            }
            // stage issues: 2 B-gld per phase; A[kt+2] regs in phase kc==1
            if (kt < 7) {
#pragma unroll
                for (int js = 0; js < 2; ++js) {
                    const int slot = kc * 2 + js;
                    async_cp16(wfrag + (size_t)(kt + 1) * 2048 + slot * 512 + t,
                               &BS[cur ^ 1][slot * 512 + t]);
                }
            }
            if (kc == 1 && kt < 6) {
#pragma unroll
                for (int j = 0; j < 4; ++j)
                    Anxt[j] = *(const uint4*)(asrc[j] + (kt + 2) * 32);
            }
            __builtin_amdgcn_s_barrier();
            __builtin_amdgcn_s_setprio(1);
#pragma unroll
            for (int p = 0; p < 4; ++p)
#pragma unroll
                for (int m = 0; m < 2; ++m)
#pragma unroll
                    for (int j = 0; j < 4; ++j) {
                        const bf16x8 pa = (p & 2) ? al[m] : ah[m];
                        const bf16x8 pb = (p & 1) ? bl[j] : bh[j];
                        acc[m][j] = __builtin_amdgcn_mfma_f32_32x32x16_bf16(pa, pb, acc[m][j], 0, 0, 0);
                    }
            __builtin_amdgcn_s_setprio(0);
            __builtin_amdgcn_s_barrier();
        }
        // ---- kt tail: land A[kt+1] regs -> ds_write; land B[kt+1]; one barrier
        if (kt < 7) {
            if (kt < 6) asm volatile("s_waitcnt vmcnt(8)" ::: "memory");
            else        asm volatile("s_waitcnt vmcnt(4)" ::: "memory");
#pragma unroll
            for (int j = 0; j < 4; ++j) *(uint4*)&AS[cur ^ 1][alds[j]] = Acur[j];
            if (kt < 6) {
#pragma unroll
                for (int j = 0; j < 4; ++j) Acur[j] = Anxt[j];
            }
            asm volatile("s_waitcnt lgkmcnt(0)" ::: "memory");
            __builtin_amdgcn_sched_barrier(0);
            if (kt < 6) asm volatile("s_waitcnt vmcnt(4)" ::: "memory");
            else        asm volatile("s_waitcnt vmcnt(0)" ::: "memory");
            __builtin_amdgcn_s_barrier();
        }
    }

    // ---- epilogue: cross-cg LN exchange, SiLU, score, bin argmax
    float gE[4], beE[4], vE[4];
#pragma unroll
    for (int j = 0; j < 4; ++j) {
        const int c = cg * 128 + j * 32 + c31;
        gE[j] = g1[c]; beE[j] = be1[c]; vE[j] = v[c];
    }
    __syncthreads();
#pragma unroll
    for (int m = 0; m < 2; ++m)
#pragma unroll
        for (int reg = 0; reg < 16; ++reg) {
            float sx = 0.f, sq = 0.f;
#pragma unroll
            for (int j = 0; j < 4; ++j) {
                const float x = acc[m][j][reg];
                sx += x; sq = fmaf(x, x, sq);
            }
#pragma unroll
            for (int msk = 1; msk <= 16; msk <<= 1) {
                sx += __shfl_xor(sx, msk);
                sq += __shfl_xor(sq, msk);
            }
            if (c31 == 0) {
                const int rowB = rg * 64 + m * 32 + (reg & 3) + 8 * (reg >> 2) + 4 * h;
                sums2[rowB][cg * 2 + 0] = sx;
                sums2[rowB][cg * 2 + 1] = sq;
            }
        }
    __syncthreads();
#pragma unroll
    for (int m = 0; m < 2; ++m)
#pragma unroll
        for (int reg = 0; reg < 16; ++reg) {
            const int rowB = rg * 64 + m * 32 + (reg & 3) + 8 * (reg >> 2) + 4 * h;
            const float4 s4 = *(const float4*)&sums2[rowB][0];
            const float mu = (s4.x + s4.z) * (1.f / 256.f);
            const float var = (s4.y + s4.w) * (1.f / 256.f) - mu * mu;
            const float rs = 1.f / sqrtf(var + 1e-5f);
            float dot = 0.f;
#pragma unroll
            for (int j = 0; j < 4; ++j) {
                const float hv = (acc[m][j][reg] - mu) * rs * gE[j] + beE[j];
                const float sg = 1.f / (1.f + __expf(-hv));
                dot = fmaf(vE[j], hv * sg, dot);
            }
#pragma unroll
            for (int msk = 1; msk <= 16; msk <<= 1) dot += __shfl_xor(dot, msk);
            if (c31 == 0) dot2[rowB][cg] = dot;
        }
    __syncthreads();
    if (t < 256) {
        const int row = R0T + t;
        if (row < total) {
            const float sc = dot2[t][0] + dot2[t][1] + v[256];
            scores[row] = sc;
            const float Wf = (float)Wp[0];
            const int Hi = Hp[0];
            const float t02 = (float)(0.2 * (double)Hi);
            const float t05 = (float)(0.5 * (double)Hi);
            const float t03 = (float)(0.3 * (double)Hi);
            const float x = kpts[(size_t)row * 2 + 0];
            const float y = kpts[(size_t)row * 2 + 1];
            int g = -1;
            if (y > t05) {
                int bgx = (int)(x / Wf * 16.f); bgx = min(max(bgx, 0), 15);
                int bgy = (int)((y - t05) / t05 * 6.f); bgy = min(max(bgy, 0), 5);
                g = 32 + bgy * 16 + bgx;
            } else if (y > t02) {
                int mgx = (int)(x / Wf * 8.f); mgx = min(max(mgx, 0), 7);
                int mgy = (int)((y - t02) / t03 * 4.f); mgy = min(max(mgy, 0), 3);
                g = mgy * 8 + mgx;
            }
            if (g >= 0) {
                const int bb = row / N;
                const int n = row - bb * N;
                const unsigned long long pk =
                    ((unsigned long long)score_key(sc) << 32) | (unsigned)(~(unsigned)n);
                atomicMax(&bins[bb * 128 + g], pk);
            }
        }
    }
}

__global__ __launch_bounds__(256) void finalize_kernel(
    const float* __restrict__ scores, const unsigned long long* __restrict__ bins,
    const float* __restrict__ desc, const float* __restrict__ kpts,
    const int* __restrict__ tkp, float* __restrict__ out, int B, int N)
{
    const int b = blockIdx.x, t = threadIdx.x;
    const int topk = tkp[0];
    __shared__ int selL[512];
    __shared__ int nselS;
    __shared__ unsigned long long red[256];
    __shared__ unsigned long long binL[128];

    if (t < 128) binL[t] = bins[b * 128 + t];
    __syncthreads();
    if (t == 0) {
        int c = 0;
        for (int i = 0; i < 128; ++i)
            if ((binL[i] >> 32) != 0ULL) selL[c++] = (int)(~(unsigned)binL[i]);
        nselS = c;
    }
    __syncthreads();
    const int nsel = nselS;

    for (int need = nsel; need < topk; ++need) {
        unsigned long long best = 0ULL;
        for (int i = t; i < N; i += 256) {
            bool taken = false;
            for (int s2 = 0; s2 < need; ++s2)
                if (selL[s2] == i) { taken = true; break; }
            if (!taken) {
                const unsigned long long pk =
                    ((unsigned long long)score_key(scores[(size_t)b * N + i]) << 32)
                    | (unsigned)(~(unsigned)i);
                if (pk > best) best = pk;
            }
        }
        red[t] = best;
        __syncthreads();
        for (int off = 128; off > 0; off >>= 1) {
            if (t < off) { if (red[t + off] > red[t]) red[t] = red[t + off]; }
            __syncthreads();
        }
        if (t == 0) selL[need] = (int)(~(unsigned)red[0]);
        __syncthreads();
    }

    float* o_feat = out;
    float* o_kpts = out + (size_t)B * topk * 256;
    float* o_idx  = out + (size_t)B * topk * 258;
    for (int e = t; e < topk * 64; e += 256) {
        const int j = e >> 6, q4 = e & 63;
        const int n = selL[j];
        *(float4*)&o_feat[((size_t)b * topk + j) * 256 + q4 * 4] =
            *(const float4*)&desc[((size_t)b * N + n) * 256 + q4 * 4];
    }
    for (int j = t; j < topk; j += 256) {
        const int n = selL[j];
        o_kpts[((size_t)b * topk + j) * 2 + 0] = kpts[((size_t)b * N + n) * 2 + 0];
        o_kpts[((size_t)b * topk + j) * 2 + 1] = kpts[((size_t)b * N + n) * 2 + 1];
        o_idx[(size_t)b * topk + j] = (float)n;
    }
}

extern "C" void kernel_launch(void* const* d_in, const int* in_sizes, int n_in,
                              void* d_out, int out_size, void* d_ws, size_t ws_size,
                              hipStream_t stream) {
    const float* kpts = (const float*)d_in[0];
    const float* desc = (const float*)d_in[1];
    const int*   Hp   = (const int*)d_in[2];
    const int*   Wp   = (const int*)d_in[3];
    const int*   tkp  = (const int*)d_in[4];
    const float* W1   = (const float*)d_in[5];
    const float* b1   = (const float*)d_in[6];
    const float* g1   = (const float*)d_in[7];
    const float* be1  = (const float*)d_in[8];
    const float* W2   = (const float*)d_in[9];
    const float* b2   = (const float*)d_in[10];
    const float* Ws   = (const float*)d_in[11];
    const float* bs   = (const float*)d_in[12];

    const int total = in_sizes[1] / 256;   // B*N
    const int BT    = out_size / 259;      // B*topk
    const int B     = BT / 128;
    const int N     = total / B;
    const int OUT   = in_sizes[11];

    float* ws_v      = (float*)d_ws;
    float* ws_scores = ws_v + 512;
    size_t off = ((size_t)(512 + total) * 4 + 255) & ~(size_t)255;
    unsigned long long* ws_bins = (unsigned long long*)((char*)d_ws + off);
    size_t off2 = (off + (size_t)B * 128 * 8 + 255) & ~(size_t)255;
    uint4* ws_wfrag = (uint4*)((char*)d_ws + off2);        // 256 KB

    prep_kernel<<<1, 256, 0, stream>>>(W2, b2, Ws, bs, ws_v, OUT);
    prep_w1frag<<<64, 256, 0, stream>>>(W1, ws_wfrag);
    init_bins<<<(B * 128 + 255) / 256, 256, 0, stream>>>(ws_bins, B * 128);
    score_kernel<<<(total + 255) / 256, 512, 0, stream>>>(
        desc, kpts, ws_wfrag, b1, g1, be1, Hp, Wp, ws_v, ws_scores, ws_bins, N, total);
    finalize_kernel<<<B, 256, 0, stream>>>(ws_scores, ws_bins, desc, kpts, tkp,
                                           (float*)d_out, B, N);
}